// Round 21
// baseline (646.401 us; speedup 1.0000x reference)
//
#include <hip/hip_runtime.h>
#include <hip/hip_bf16.h>
#include <math.h>

#define Bz 2
#define Tz 2048
#define Dz 1024
#define Hz 16
#define DHz 64
#define BNz 1024
#define TOPKz 64
#define QBLK 16
#define CAND_MAX 176
#define BAND 8e-5f    // ambiguity half-band on RAW scores (verified r5-r20)
#define SLO  -20.0f
#define SBINW 0.15625f
#define SBINR 6.4f
#define LDSB 40

typedef __attribute__((ext_vector_type(8))) short bf16x8;
typedef __attribute__((ext_vector_type(4))) short s16x4;
typedef __attribute__((ext_vector_type(4))) float f32x4;

__device__ __forceinline__ short f2bf(float f) {     // RNE f32 -> bf16
  unsigned u = __float_as_uint(f);
  return (short)((u + 0x7FFFu + ((u >> 16) & 1u)) >> 16);
}
__device__ __forceinline__ float bf2f(short b) {
  return __uint_as_float(((unsigned)(unsigned short)b) << 16);
}
__device__ __forceinline__ unsigned f2s(float f) {   // order-preserving f32->u32
  unsigned u = __float_as_uint(f);
  return (u & 0x80000000u) ? ~u : (u | 0x80000000u);
}
__device__ __forceinline__ float s2f(unsigned u) {
  return __uint_as_float((u & 0x80000000u) ? (u & 0x7FFFFFFFu) : ~u);
}

// ---- split3: f32 -> (hi, mid, lo) bf16, elementwise -----------------------
__global__ __launch_bounds__(256) void split3(
    const float* __restrict__ in, short* __restrict__ hh,
    short* __restrict__ mm, short* __restrict__ ll, int n4)
{
  int i = blockIdx.x * 256 + threadIdx.x;
  if (i >= n4) return;
  float4 v = ((const float4*)in)[i];
  float vv[4] = {v.x, v.y, v.z, v.w};
  s16x4 h4, m4, l4;
#pragma unroll
  for (int e = 0; e < 4; ++e) {
    short h = f2bf(vv[e]);
    float r1 = vv[e] - bf2f(h);
    short m = f2bf(r1);
    float r2 = r1 - bf2f(m);
    h4[e] = h; m4[e] = m; l4[e] = f2bf(r2);
  }
  ((s16x4*)hh)[i] = h4;
  ((s16x4*)mm)[i] = m4;
  ((s16x4*)ll)[i] = l4;
}

// ---- QKV GEMM from PRE-SPLIT bf16 panels (byte-identical to r20) ----------
__global__ __launch_bounds__(256) void qkv_gemm_v2(
    const short* __restrict__ Axh, const short* __restrict__ Axm,
    const short* __restrict__ Axl, const short* __restrict__ Bwh,
    const short* __restrict__ Bwm, const short* __restrict__ Bwl,
    const float* __restrict__ bias,
    float* __restrict__ q32, float* __restrict__ k32,
    short* __restrict__ kbf, float* __restrict__ v32)
{
  __shared__ __align__(16) short Ah[128][LDSB];
  __shared__ __align__(16) short Am[128][LDSB];
  __shared__ __align__(16) short Al[128][LDSB];
  __shared__ __align__(16) short Bh[64][LDSB];
  __shared__ __align__(16) short Bm[64][LDSB];
  __shared__ __align__(16) short Bl[64][LDSB];

  const int tid = threadIdx.x;
  const int lane = tid & 63, wid = tid >> 6;
  const int m0 = blockIdx.y * 128, n0 = blockIdx.x * 64;
  const int bcol = lane & 15, lgrp = lane >> 4;

  f32x4 acch[2][4], accl[2][4];
#pragma unroll
  for (int ms = 0; ms < 2; ++ms)
#pragma unroll
    for (int nt = 0; nt < 4; ++nt) {
      acch[ms][nt] = (f32x4){0.f, 0.f, 0.f, 0.f};
      accl[ms][nt] = (f32x4){0.f, 0.f, 0.f, 0.f};
    }

  const int arow = tid >> 1, ak = (tid & 1) * 16;
  const int brow = tid >> 2, bk = (tid & 3) * 8;
  const size_t aoff = (size_t)(m0 + arow) * Dz + ak;
  const size_t boff = (size_t)(n0 + brow) * Dz + bk;

  for (int kt = 0; kt < Dz; kt += 32) {
    bf16x8 ah0 = *(const bf16x8*)(Axh + aoff + kt);
    bf16x8 ah1 = *(const bf16x8*)(Axh + aoff + kt + 8);
    bf16x8 am0 = *(const bf16x8*)(Axm + aoff + kt);
    bf16x8 am1 = *(const bf16x8*)(Axm + aoff + kt + 8);
    bf16x8 al0 = *(const bf16x8*)(Axl + aoff + kt);
    bf16x8 al1 = *(const bf16x8*)(Axl + aoff + kt + 8);
    bf16x8 bh8 = *(const bf16x8*)(Bwh + boff + kt);
    bf16x8 bm8 = *(const bf16x8*)(Bwm + boff + kt);
    bf16x8 bl8 = *(const bf16x8*)(Bwl + boff + kt);
    __syncthreads();
    *(bf16x8*)&Ah[arow][ak] = ah0;  *(bf16x8*)&Ah[arow][ak+8] = ah1;
    *(bf16x8*)&Am[arow][ak] = am0;  *(bf16x8*)&Am[arow][ak+8] = am1;
    *(bf16x8*)&Al[arow][ak] = al0;  *(bf16x8*)&Al[arow][ak+8] = al1;
    *(bf16x8*)&Bh[brow][bk] = bh8;
    *(bf16x8*)&Bm[brow][bk] = bm8;
    *(bf16x8*)&Bl[brow][bk] = bl8;
    __syncthreads();

    bf16x8 ahf[2], amf[2], alf[2];
#pragma unroll
    for (int ms = 0; ms < 2; ++ms) {
      int rr = wid*32 + ms*16 + bcol;
      ahf[ms] = *(const bf16x8*)&Ah[rr][lgrp*8];
      amf[ms] = *(const bf16x8*)&Am[rr][lgrp*8];
      alf[ms] = *(const bf16x8*)&Al[rr][lgrp*8];
    }
#pragma unroll
    for (int nt = 0; nt < 4; ++nt) {
      int nr = nt*16 + bcol;
      bf16x8 bh = *(const bf16x8*)&Bh[nr][lgrp*8];
      bf16x8 bm = *(const bf16x8*)&Bm[nr][lgrp*8];
      bf16x8 bl = *(const bf16x8*)&Bl[nr][lgrp*8];
#pragma unroll
      for (int ms = 0; ms < 2; ++ms) {
        acch[ms][nt] = __builtin_amdgcn_mfma_f32_16x16x32_bf16(ahf[ms], bh, acch[ms][nt], 0, 0, 0);
        accl[ms][nt] = __builtin_amdgcn_mfma_f32_16x16x32_bf16(ahf[ms], bm, accl[ms][nt], 0, 0, 0);
        accl[ms][nt] = __builtin_amdgcn_mfma_f32_16x16x32_bf16(amf[ms], bh, accl[ms][nt], 0, 0, 0);
        accl[ms][nt] = __builtin_amdgcn_mfma_f32_16x16x32_bf16(amf[ms], bm, accl[ms][nt], 0, 0, 0);
        accl[ms][nt] = __builtin_amdgcn_mfma_f32_16x16x32_bf16(ahf[ms], bl, accl[ms][nt], 0, 0, 0);
        accl[ms][nt] = __builtin_amdgcn_mfma_f32_16x16x32_bf16(alf[ms], bh, accl[ms][nt], 0, 0, 0);
      }
    }
  }

#pragma unroll
  for (int ms = 0; ms < 2; ++ms)
#pragma unroll
    for (int nt = 0; nt < 4; ++nt)
#pragma unroll
      for (int rv = 0; rv < 4; ++rv) {
        int m = m0 + wid*32 + ms*16 + lgrp*4 + rv;
        int n = n0 + nt*16 + bcol;
        double val = (double)acch[ms][nt][rv] + (double)accl[ms][nt][rv] + (double)bias[n];
        int bb = m >> 11;
        int t = m & 2047;
        if (n < BNz) {
          int h = n >> 6, d = n & 63;
          q32[(((size_t)(bb*Hz + h))*Tz + t)*DHz + d] = (float)val;
        } else if (n < 2*BNz) {
          int h = (n - BNz) >> 6, d = n & 63;
          size_t bh = (size_t)(bb*Hz + h);
          float vf = (float)val;
          k32[(bh*Tz + t)*DHz + d] = vf;
          kbf[(bh*Tz + t)*DHz + d] = f2bf(vf);
        } else {
          int h = (n - 2*BNz) >> 6, d = n & 63;
          v32[(((size_t)(bb*Hz + h))*Tz + t)*DHz + d] = (float)val;
        }
      }
}

// ---- proj GEMM from PRE-SPLIT bf16 panels (byte-identical to r20) ---------
__global__ __launch_bounds__(256) void proj_gemm_v2(
    const short* __restrict__ Ayh, const short* __restrict__ Aym,
    const short* __restrict__ Ayl, const short* __restrict__ Bwh,
    const short* __restrict__ Bwm, const short* __restrict__ Bwl,
    const float* __restrict__ bias, float* __restrict__ out)
{
  __shared__ __align__(16) short Ah[128][LDSB];
  __shared__ __align__(16) short Am[128][LDSB];
  __shared__ __align__(16) short Al[128][LDSB];
  __shared__ __align__(16) short Bh[64][LDSB];
  __shared__ __align__(16) short Bm[64][LDSB];
  __shared__ __align__(16) short Bl[64][LDSB];

  const int tid = threadIdx.x;
  const int lane = tid & 63, wid = tid >> 6;
  const int m0 = blockIdx.y * 128, n0 = blockIdx.x * 64;
  const int bcol = lane & 15, lgrp = lane >> 4;

  f32x4 acch[2][4], accl[2][4];
#pragma unroll
  for (int ms = 0; ms < 2; ++ms)
#pragma unroll
    for (int nt = 0; nt < 4; ++nt) {
      acch[ms][nt] = (f32x4){0.f, 0.f, 0.f, 0.f};
      accl[ms][nt] = (f32x4){0.f, 0.f, 0.f, 0.f};
    }

  const int arow = tid >> 1, ak = (tid & 1) * 16;
  const int brow = tid >> 2, bk = (tid & 3) * 8;
  const size_t aoff = (size_t)(m0 + arow) * Dz + ak;
  const size_t boff = (size_t)(n0 + brow) * Dz + bk;

  for (int kt = 0; kt < Dz; kt += 32) {
    bf16x8 ah0 = *(const bf16x8*)(Ayh + aoff + kt);
    bf16x8 ah1 = *(const bf16x8*)(Ayh + aoff + kt + 8);
    bf16x8 am0 = *(const bf16x8*)(Aym + aoff + kt);
    bf16x8 am1 = *(const bf16x8*)(Aym + aoff + kt + 8);
    bf16x8 al0 = *(const bf16x8*)(Ayl + aoff + kt);
    bf16x8 al1 = *(const bf16x8*)(Ayl + aoff + kt + 8);
    bf16x8 bh8 = *(const bf16x8*)(Bwh + boff + kt);
    bf16x8 bm8 = *(const bf16x8*)(Bwm + boff + kt);
    bf16x8 bl8 = *(const bf16x8*)(Bwl + boff + kt);
    __syncthreads();
    *(bf16x8*)&Ah[arow][ak] = ah0;  *(bf16x8*)&Ah[arow][ak+8] = ah1;
    *(bf16x8*)&Am[arow][ak] = am0;  *(bf16x8*)&Am[arow][ak+8] = am1;
    *(bf16x8*)&Al[arow][ak] = al0;  *(bf16x8*)&Al[arow][ak+8] = al1;
    *(bf16x8*)&Bh[brow][bk] = bh8;
    *(bf16x8*)&Bm[brow][bk] = bm8;
    *(bf16x8*)&Bl[brow][bk] = bl8;
    __syncthreads();

    bf16x8 ahf[2], amf[2], alf[2];
#pragma unroll
    for (int ms = 0; ms < 2; ++ms) {
      int rr = wid*32 + ms*16 + bcol;
      ahf[ms] = *(const bf16x8*)&Ah[rr][lgrp*8];
      amf[ms] = *(const bf16x8*)&Am[rr][lgrp*8];
      alf[ms] = *(const bf16x8*)&Al[rr][lgrp*8];
    }
#pragma unroll
    for (int nt = 0; nt < 4; ++nt) {
      int nr = nt*16 + bcol;
      bf16x8 bh = *(const bf16x8*)&Bh[nr][lgrp*8];
      bf16x8 bm = *(const bf16x8*)&Bm[nr][lgrp*8];
      bf16x8 bl = *(const bf16x8*)&Bl[nr][lgrp*8];
#pragma unroll
      for (int ms = 0; ms < 2; ++ms) {
        acch[ms][nt] = __builtin_amdgcn_mfma_f32_16x16x32_bf16(ahf[ms], bh, acch[ms][nt], 0, 0, 0);
        accl[ms][nt] = __builtin_amdgcn_mfma_f32_16x16x32_bf16(ahf[ms], bm, accl[ms][nt], 0, 0, 0);
        accl[ms][nt] = __builtin_amdgcn_mfma_f32_16x16x32_bf16(amf[ms], bh, accl[ms][nt], 0, 0, 0);
        accl[ms][nt] = __builtin_amdgcn_mfma_f32_16x16x32_bf16(amf[ms], bm, accl[ms][nt], 0, 0, 0);
        accl[ms][nt] = __builtin_amdgcn_mfma_f32_16x16x32_bf16(ahf[ms], bl, accl[ms][nt], 0, 0, 0);
        accl[ms][nt] = __builtin_amdgcn_mfma_f32_16x16x32_bf16(alf[ms], bh, accl[ms][nt], 0, 0, 0);
      }
    }
  }

#pragma unroll
  for (int ms = 0; ms < 2; ++ms)
#pragma unroll
    for (int nt = 0; nt < 4; ++nt)
#pragma unroll
      for (int rv = 0; rv < 4; ++rv) {
        int m = m0 + wid*32 + ms*16 + lgrp*4 + rv;
        int n = n0 + nt*16 + bcol;
        out[(size_t)m * Dz + n] = (acch[ms][nt][rv] + accl[ms][nt][rv]) + bias[n];
      }
}

// ---- attention v13 = r18/r20 attn with the LDS histogram replaced by an
//      ATOMIC-FREE 8-step bisection over register-cached u8 bins.
//      bstar identical -> downstream (collect/rescore/rank/band/AV) and
//      output bit-identical; removes 32K same-address LDS atomics per block.
__global__ __launch_bounds__(256) void attn_topk(
    const float* __restrict__ q32g, const float* __restrict__ k32g,
    const short* __restrict__ kbfg, const float* __restrict__ v32,
    float* __restrict__ y)
{
  __shared__ float q_s[QBLK][DHz];
  __shared__ __align__(16) unsigned char ubuf[QBLK*CAND_MAX*6];  // candv/candidx
  __shared__ int rcnt[QBLK];
  __shared__ int rlo[QBLK], rhi[QBLK], rmid[QBLK];
  __shared__ int bstar_s[QBLK];
  __shared__ int candcnt[QBLK];

  float* candv = (float*)ubuf;                        // [16][CAND_MAX]
  unsigned short* candidx = (unsigned short*)(ubuf + QBLK*CAND_MAX*4);

  const int tid = threadIdx.x;
  const int bid0 = blockIdx.x;
  const int bh_f = (bid0 & 7) + 8 * (bid0 >> 10);
  const int qbf = (bid0 >> 3) & 127;
  const int h = bh_f & 15;
  const int bb = bh_f >> 4;
  const size_t bh = (size_t)(bb * Hz + h);
  const float* qg = q32g + (bh * Tz + (size_t)qbf * QBLK) * DHz;
  const float* kg32 = k32g + bh * Tz * DHz;
  const short* kb = kbfg + bh * Tz * DHz;
  const float* vg = v32 + bh * Tz * DHz;

  if (tid < QBLK) {
    candcnt[tid] = 0; rcnt[tid] = 0;
    rlo[tid] = 0; rhi[tid] = 256; rmid[tid] = 128;
  }
  {
    int r = tid >> 4, d4 = (tid & 15) * 4;
    *(float4*)&q_s[r][d4] = *(const float4*)&qg[r*DHz + d4];
  }
  __syncthreads();                                    // barrier 1

  const int lane = tid & 63;
  const int wid = tid >> 6;
  const int bcol = lane & 15;
  const int lgrp = lane >> 4;
  bf16x8 aF0, aF1;
#pragma unroll
  for (int e = 0; e < 8; ++e) {
    aF0[e] = f2bf(q_s[bcol][lgrp*8 + e]);
    aF1[e] = f2bf(q_s[bcol][32 + lgrp*8 + e]);
  }
  const int t0base = wid * 512;

  // ---- single MFMA pass: pack bins into 32 registers (NO LDS atomics) ----
  unsigned binreg[32];
#pragma unroll 4
  for (int tt = 0; tt < 32; ++tt) {
    const short* kbp = kb + (size_t)(t0base + tt*16 + bcol) * DHz;
    bf16x8 b0 = *(const bf16x8*)(kbp + lgrp*8);
    bf16x8 b1 = *(const bf16x8*)(kbp + 32 + lgrp*8);
    f32x4 c = {0.f, 0.f, 0.f, 0.f};
    c = __builtin_amdgcn_mfma_f32_16x16x32_bf16(aF0, b0, c, 0, 0, 0);
    c = __builtin_amdgcn_mfma_f32_16x16x32_bf16(aF1, b1, c, 0, 0, 0);
    unsigned bw = 0u;
#pragma unroll
    for (int j = 0; j < 4; ++j) {
      int bin = (int)((c[j] - SLO) * SBINR);
      bin = bin < 0 ? 0 : (bin > 255 ? 255 : bin);
      bw |= ((unsigned)bin) << (8*j);
    }
    binreg[tt] = bw;
  }

  // ---- 8-step bisection: bstar = largest b with count(bin >= b) >= 64 ----
  // Identical result to the histogram suffix-scan (exact integer search).
#pragma unroll
  for (int it = 0; it < 8; ++it) {
    int bc[4];
#pragma unroll
    for (int j = 0; j < 4; ++j) bc[j] = rmid[lgrp*4 + j];
    int cnt[4] = {0, 0, 0, 0};
#pragma unroll
    for (int tt = 0; tt < 32; ++tt) {
      unsigned bw = binreg[tt];
#pragma unroll
      for (int j = 0; j < 4; ++j)
        cnt[j] += ((int)((bw >> (8*j)) & 255u) >= bc[j]) ? 1 : 0;
    }
#pragma unroll
    for (int m = 1; m < 16; m <<= 1)
#pragma unroll
      for (int j = 0; j < 4; ++j) cnt[j] += __shfl_xor(cnt[j], m);
    if (bcol == 0) {
#pragma unroll
      for (int j = 0; j < 4; ++j) atomicAdd(&rcnt[lgrp*4 + j], cnt[j]);
    }
    __syncthreads();
    if (tid < QBLK) {
      int c = rcnt[tid]; rcnt[tid] = 0;
      if (c >= TOPKz) rlo[tid] = rmid[tid]; else rhi[tid] = rmid[tid];
      rmid[tid] = (rlo[tid] + rhi[tid]) >> 1;
    }
    __syncthreads();
  }
  if (tid < QBLK) bstar_s[tid] = rlo[tid];
  __syncthreads();

  // ---- collect from REGISTERS: bin >= bstar-1 ----
  {
    int bc[4];
#pragma unroll
    for (int j = 0; j < 4; ++j) {
      int b = bstar_s[lgrp*4 + j] - 1;
      bc[j] = b < 0 ? 0 : b;
    }
#pragma unroll
    for (int tt = 0; tt < 32; ++tt) {
      unsigned bw = binreg[tt];
#pragma unroll
      for (int j = 0; j < 4; ++j) {
        int bin = (int)((bw >> (8*j)) & 255u);
        if (bin >= bc[j]) {
          int r = lgrp*4 + j;
          int p = atomicAdd(&candcnt[r], 1);
          if (p < CAND_MAX) candidx[r*CAND_MAX + p] = (unsigned short)(t0base + tt*16 + bcol);
        }
      }
    }
  }
  __syncthreads();                                    // last barrier

  // ==== group-local: rescore (f32 loads, f64 accum) / rank / band / AV ====
  {
    const int r = tid >> 4, i16 = tid & 15;
    int n = candcnt[r]; if (n > CAND_MAX) n = CAND_MAX;

    for (int i = i16; i < n; i += 16) {
      int col = (int)candidx[r*CAND_MAX + i];
      const float* kpd = kg32 + (size_t)col * DHz;
      double s = 0.0;
#pragma unroll
      for (int d = 0; d < DHz; d += 4) {
        float4 k4 = *(const float4*)(kpd + d);
        s = fma((double)q_s[r][d+0], (double)k4.x, s);
        s = fma((double)q_s[r][d+1], (double)k4.y, s);
        s = fma((double)q_s[r][d+2], (double)k4.z, s);
        s = fma((double)q_s[r][d+3], (double)k4.w, s);
      }
      candv[r*CAND_MAX + i] = (float)s;
    }

    float myv[11];
    float mx = -3.0e38f;
#pragma unroll
    for (int j = 0; j < 11; ++j) {
      int i = i16 + j*16;
      float x = (i < n) ? candv[r*CAND_MAX + i] : -3.0e38f;
      myv[j] = x;
      mx = fmaxf(mx, x);
    }
#pragma unroll
    for (int m = 1; m < 16; m <<= 1) mx = fmaxf(mx, __shfl_xor(mx, m));

    float mn = 3.0e38f;
#pragma unroll
    for (int j = 0; j < 11; ++j) {
      int i = i16 + j*16;
      if (i < n) mn = fminf(mn, myv[j]);
    }
#pragma unroll
    for (int m = 1; m < 16; m <<= 1) mn = fminf(mn, __shfl_xor(mn, m));
    unsigned lo_u = f2s(mn);
    unsigned hi_u = f2s(mx) + 1u;
    while (hi_u - lo_u > 1u) {
      unsigned mid = lo_u + ((hi_u - lo_u) >> 1);
      float tv = s2f(mid);
      int cnt = 0;
#pragma unroll
      for (int j = 0; j < 11; ++j) cnt += (myv[j] >= tv) ? 1 : 0;
#pragma unroll
      for (int m = 1; m < 16; m <<= 1) cnt += __shfl_xor(cnt, m);
      if (cnt >= TOPKz) lo_u = mid; else hi_u = mid;
    }
    const float T = s2f(lo_u);

    int na = 0, nb = 0;
#pragma unroll
    for (int j = 0; j < 11; ++j) {
      float s = myv[j];
      if (s > T + BAND) na++;
      else if (s >= T - BAND) nb++;
    }
#pragma unroll
    for (int m = 1; m < 16; m <<= 1) {
      na += __shfl_xor(na, m);
      nb += __shfl_xor(nb, m);
    }
    const float wb = (float)(TOPKz - na) / (float)(nb > 0 ? nb : 1);

    float lsum = 0.f;
#pragma unroll
    for (int j = 0; j < 11; ++j) {
      int i = i16 + j*16;
      if (i < n) {
        float s = myv[j];
        float w = (s > T + BAND) ? 1.f : ((s >= T - BAND) ? wb : 0.f);
        float p = (w > 0.f) ? w * expf((s - mx) * 0.125f) : 0.f;
        candv[r*CAND_MAX + i] = p;
        lsum += p;
      }
    }
#pragma unroll
    for (int m = 1; m < 16; m <<= 1) lsum += __shfl_xor(lsum, m);
    const float rd = 1.0f / lsum;

    const int dg = i16 * 4;
    float4 o = make_float4(0.f, 0.f, 0.f, 0.f);
    for (int i = 0; i < n; ++i) {
      float p = candv[r*CAND_MAX + i];
      int idx = (int)candidx[r*CAND_MAX + i];
      float4 vv = *(const float4*)&vg[(size_t)idx*DHz + dg];
      float pw = p * rd;
      o.x = fmaf(pw, vv.x, o.x);
      o.y = fmaf(pw, vv.y, o.y);
      o.z = fmaf(pw, vv.z, o.z);
      o.w = fmaf(pw, vv.w, o.w);
    }
    float* yo = y + ((size_t)bb*Tz + (size_t)qbf*QBLK + r) * BNz + h*DHz + dg;
    *(float4*)yo = o;
  }
}

extern "C" void kernel_launch(void* const* d_in, const int* in_sizes, int n_in,
                              void* d_out, int out_size, void* d_ws, size_t ws_size,
                              hipStream_t stream)
{
  const float* x      = (const float*)d_in[0];
  const float* w_qkv  = (const float*)d_in[1];
  const float* b_qkv  = (const float*)d_in[2];
  const float* w_proj = (const float*)d_in[3];
  const float* b_proj = (const float*)d_in[4];
  float* out = (float*)d_out;

  const size_t E  = (size_t)Bz * Tz * Dz;        // 4,194,304
  const size_t Wq = (size_t)3 * BNz * Dz;        // 3,145,728
  const size_t Wp = (size_t)Dz * BNz;            // 1,048,576

  float* q32 = (float*)d_ws;           // 16 MB
  float* k32 = q32 + E;                // 16 MB
  short* kbf = (short*)(k32 + E);      // 8 MB
  float* v32 = (float*)(kbf + E);      // 16 MB
  float* y   = v32 + E;                // 16 MB
  short* sAh = (short*)(y + E);        // 8 MB
  short* sAm = sAh + E;                // 8 MB
  short* sAl = sAm + E;                // 8 MB
  short* sBh = sAl + E;                // 6 MB
  short* sBm = sBh + Wq;               // 6 MB
  short* sBl = sBm + Wq;               // 6 MB  (total 114 MB)

  split3<<<(int)(E/4/256), 256, 0, stream>>>(x, sAh, sAm, sAl, (int)(E/4));
  split3<<<(int)(Wq/4/256), 256, 0, stream>>>(w_qkv, sBh, sBm, sBl, (int)(Wq/4));
  qkv_gemm_v2<<<dim3((3*BNz)/64, (Bz*Tz)/128), 256, 0, stream>>>(
      sAh, sAm, sAl, sBh, sBm, sBl, b_qkv, q32, k32, kbf, v32);
  attn_topk<<<Bz*Hz*(Tz/QBLK), 256, 0, stream>>>(q32, k32, kbf, v32, y);
  split3<<<(int)(E/4/256), 256, 0, stream>>>(y, sAh, sAm, sAl, (int)(E/4));
  split3<<<(int)(Wp/4/256), 256, 0, stream>>>(w_proj, sBh, sBm, sBl, (int)(Wp/4));
  proj_gemm_v2<<<dim3(Dz/64, (Bz*Tz)/128), 256, 0, stream>>>(
      sAh, sAm, sAl, sBh, sBm, sBl, b_proj, out);
}

// Round 22
// 601.189 us; speedup vs baseline: 1.0752x; 1.0752x over previous
//
#include <hip/hip_runtime.h>
#include <hip/hip_bf16.h>
#include <math.h>

#define Bz 2
#define Tz 2048
#define Dz 1024
#define Hz 16
#define DHz 64
#define BNz 1024
#define TOPKz 64
#define QBLK 16
#define CAND_MAX 176
#define BAND 8e-5f    // ambiguity half-band on RAW scores (verified r5-r21)
#define SLO  -20.0f
#define SBINW 0.15625f
#define SBINR 6.4f
#define LDSB 40
#define HSTR 257

typedef __attribute__((ext_vector_type(8))) short bf16x8;
typedef __attribute__((ext_vector_type(4))) short s16x4;
typedef __attribute__((ext_vector_type(4))) float f32x4;

__device__ __forceinline__ short f2bf(float f) {     // RNE f32 -> bf16
  unsigned u = __float_as_uint(f);
  return (short)((u + 0x7FFFu + ((u >> 16) & 1u)) >> 16);
}
__device__ __forceinline__ float bf2f(short b) {
  return __uint_as_float(((unsigned)(unsigned short)b) << 16);
}
__device__ __forceinline__ unsigned f2s(float f) {   // order-preserving f32->u32
  unsigned u = __float_as_uint(f);
  return (u & 0x80000000u) ? ~u : (u | 0x80000000u);
}
__device__ __forceinline__ float s2f(unsigned u) {
  return __uint_as_float((u & 0x80000000u) ? (u & 0x7FFFFFFFu) : ~u);
}

// ---- split3: f32 -> (hi, mid, lo) bf16, elementwise (hoisted from GEMMs) --
__global__ __launch_bounds__(256) void split3(
    const float* __restrict__ in, short* __restrict__ hh,
    short* __restrict__ mm, short* __restrict__ ll, int n4)
{
  int i = blockIdx.x * 256 + threadIdx.x;
  if (i >= n4) return;
  float4 v = ((const float4*)in)[i];
  float vv[4] = {v.x, v.y, v.z, v.w};
  s16x4 h4, m4, l4;
#pragma unroll
  for (int e = 0; e < 4; ++e) {
    short h = f2bf(vv[e]);
    float r1 = vv[e] - bf2f(h);
    short m = f2bf(r1);
    float r2 = r1 - bf2f(m);
    h4[e] = h; m4[e] = m; l4[e] = f2bf(r2);
  }
  ((s16x4*)hh)[i] = h4;
  ((s16x4*)mm)[i] = m4;
  ((s16x4*)ll)[i] = l4;
}

// ---- QKV GEMM from PRE-SPLIT bf16 panels (r20 optimum) --------------------
__global__ __launch_bounds__(256) void qkv_gemm_v2(
    const short* __restrict__ Axh, const short* __restrict__ Axm,
    const short* __restrict__ Axl, const short* __restrict__ Bwh,
    const short* __restrict__ Bwm, const short* __restrict__ Bwl,
    const float* __restrict__ bias,
    float* __restrict__ q32, float* __restrict__ k32,
    short* __restrict__ kbf, float* __restrict__ v32)
{
  __shared__ __align__(16) short Ah[128][LDSB];
  __shared__ __align__(16) short Am[128][LDSB];
  __shared__ __align__(16) short Al[128][LDSB];
  __shared__ __align__(16) short Bh[64][LDSB];
  __shared__ __align__(16) short Bm[64][LDSB];
  __shared__ __align__(16) short Bl[64][LDSB];

  const int tid = threadIdx.x;
  const int lane = tid & 63, wid = tid >> 6;
  const int m0 = blockIdx.y * 128, n0 = blockIdx.x * 64;
  const int bcol = lane & 15, lgrp = lane >> 4;

  f32x4 acch[2][4], accl[2][4];
#pragma unroll
  for (int ms = 0; ms < 2; ++ms)
#pragma unroll
    for (int nt = 0; nt < 4; ++nt) {
      acch[ms][nt] = (f32x4){0.f, 0.f, 0.f, 0.f};
      accl[ms][nt] = (f32x4){0.f, 0.f, 0.f, 0.f};
    }

  const int arow = tid >> 1, ak = (tid & 1) * 16;
  const int brow = tid >> 2, bk = (tid & 3) * 8;
  const size_t aoff = (size_t)(m0 + arow) * Dz + ak;
  const size_t boff = (size_t)(n0 + brow) * Dz + bk;

  for (int kt = 0; kt < Dz; kt += 32) {
    bf16x8 ah0 = *(const bf16x8*)(Axh + aoff + kt);
    bf16x8 ah1 = *(const bf16x8*)(Axh + aoff + kt + 8);
    bf16x8 am0 = *(const bf16x8*)(Axm + aoff + kt);
    bf16x8 am1 = *(const bf16x8*)(Axm + aoff + kt + 8);
    bf16x8 al0 = *(const bf16x8*)(Axl + aoff + kt);
    bf16x8 al1 = *(const bf16x8*)(Axl + aoff + kt + 8);
    bf16x8 bh8 = *(const bf16x8*)(Bwh + boff + kt);
    bf16x8 bm8 = *(const bf16x8*)(Bwm + boff + kt);
    bf16x8 bl8 = *(const bf16x8*)(Bwl + boff + kt);
    __syncthreads();
    *(bf16x8*)&Ah[arow][ak] = ah0;  *(bf16x8*)&Ah[arow][ak+8] = ah1;
    *(bf16x8*)&Am[arow][ak] = am0;  *(bf16x8*)&Am[arow][ak+8] = am1;
    *(bf16x8*)&Al[arow][ak] = al0;  *(bf16x8*)&Al[arow][ak+8] = al1;
    *(bf16x8*)&Bh[brow][bk] = bh8;
    *(bf16x8*)&Bm[brow][bk] = bm8;
    *(bf16x8*)&Bl[brow][bk] = bl8;
    __syncthreads();

    bf16x8 ahf[2], amf[2], alf[2];
#pragma unroll
    for (int ms = 0; ms < 2; ++ms) {
      int rr = wid*32 + ms*16 + bcol;
      ahf[ms] = *(const bf16x8*)&Ah[rr][lgrp*8];
      amf[ms] = *(const bf16x8*)&Am[rr][lgrp*8];
      alf[ms] = *(const bf16x8*)&Al[rr][lgrp*8];
    }
#pragma unroll
    for (int nt = 0; nt < 4; ++nt) {
      int nr = nt*16 + bcol;
      bf16x8 bh = *(const bf16x8*)&Bh[nr][lgrp*8];
      bf16x8 bm = *(const bf16x8*)&Bm[nr][lgrp*8];
      bf16x8 bl = *(const bf16x8*)&Bl[nr][lgrp*8];
#pragma unroll
      for (int ms = 0; ms < 2; ++ms) {
        acch[ms][nt] = __builtin_amdgcn_mfma_f32_16x16x32_bf16(ahf[ms], bh, acch[ms][nt], 0, 0, 0);
        accl[ms][nt] = __builtin_amdgcn_mfma_f32_16x16x32_bf16(ahf[ms], bm, accl[ms][nt], 0, 0, 0);
        accl[ms][nt] = __builtin_amdgcn_mfma_f32_16x16x32_bf16(amf[ms], bh, accl[ms][nt], 0, 0, 0);
        accl[ms][nt] = __builtin_amdgcn_mfma_f32_16x16x32_bf16(amf[ms], bm, accl[ms][nt], 0, 0, 0);
        accl[ms][nt] = __builtin_amdgcn_mfma_f32_16x16x32_bf16(ahf[ms], bl, accl[ms][nt], 0, 0, 0);
        accl[ms][nt] = __builtin_amdgcn_mfma_f32_16x16x32_bf16(alf[ms], bh, accl[ms][nt], 0, 0, 0);
      }
    }
  }

#pragma unroll
  for (int ms = 0; ms < 2; ++ms)
#pragma unroll
    for (int nt = 0; nt < 4; ++nt)
#pragma unroll
      for (int rv = 0; rv < 4; ++rv) {
        int m = m0 + wid*32 + ms*16 + lgrp*4 + rv;
        int n = n0 + nt*16 + bcol;
        double val = (double)acch[ms][nt][rv] + (double)accl[ms][nt][rv] + (double)bias[n];
        int bb = m >> 11;
        int t = m & 2047;
        if (n < BNz) {
          int h = n >> 6, d = n & 63;
          q32[(((size_t)(bb*Hz + h))*Tz + t)*DHz + d] = (float)val;
        } else if (n < 2*BNz) {
          int h = (n - BNz) >> 6, d = n & 63;
          size_t bh = (size_t)(bb*Hz + h);
          float vf = (float)val;
          k32[(bh*Tz + t)*DHz + d] = vf;
          kbf[(bh*Tz + t)*DHz + d] = f2bf(vf);
        } else {
          int h = (n - 2*BNz) >> 6, d = n & 63;
          v32[(((size_t)(bb*Hz + h))*Tz + t)*DHz + d] = (float)val;
        }
      }
}

// ---- proj GEMM from PRE-SPLIT bf16 panels (r20 optimum) -------------------
__global__ __launch_bounds__(256) void proj_gemm_v2(
    const short* __restrict__ Ayh, const short* __restrict__ Aym,
    const short* __restrict__ Ayl, const short* __restrict__ Bwh,
    const short* __restrict__ Bwm, const short* __restrict__ Bwl,
    const float* __restrict__ bias, float* __restrict__ out)
{
  __shared__ __align__(16) short Ah[128][LDSB];
  __shared__ __align__(16) short Am[128][LDSB];
  __shared__ __align__(16) short Al[128][LDSB];
  __shared__ __align__(16) short Bh[64][LDSB];
  __shared__ __align__(16) short Bm[64][LDSB];
  __shared__ __align__(16) short Bl[64][LDSB];

  const int tid = threadIdx.x;
  const int lane = tid & 63, wid = tid >> 6;
  const int m0 = blockIdx.y * 128, n0 = blockIdx.x * 64;
  const int bcol = lane & 15, lgrp = lane >> 4;

  f32x4 acch[2][4], accl[2][4];
#pragma unroll
  for (int ms = 0; ms < 2; ++ms)
#pragma unroll
    for (int nt = 0; nt < 4; ++nt) {
      acch[ms][nt] = (f32x4){0.f, 0.f, 0.f, 0.f};
      accl[ms][nt] = (f32x4){0.f, 0.f, 0.f, 0.f};
    }

  const int arow = tid >> 1, ak = (tid & 1) * 16;
  const int brow = tid >> 2, bk = (tid & 3) * 8;
  const size_t aoff = (size_t)(m0 + arow) * Dz + ak;
  const size_t boff = (size_t)(n0 + brow) * Dz + bk;

  for (int kt = 0; kt < Dz; kt += 32) {
    bf16x8 ah0 = *(const bf16x8*)(Ayh + aoff + kt);
    bf16x8 ah1 = *(const bf16x8*)(Ayh + aoff + kt + 8);
    bf16x8 am0 = *(const bf16x8*)(Aym + aoff + kt);
    bf16x8 am1 = *(const bf16x8*)(Aym + aoff + kt + 8);
    bf16x8 al0 = *(const bf16x8*)(Ayl + aoff + kt);
    bf16x8 al1 = *(const bf16x8*)(Ayl + aoff + kt + 8);
    bf16x8 bh8 = *(const bf16x8*)(Bwh + boff + kt);
    bf16x8 bm8 = *(const bf16x8*)(Bwm + boff + kt);
    bf16x8 bl8 = *(const bf16x8*)(Bwl + boff + kt);
    __syncthreads();
    *(bf16x8*)&Ah[arow][ak] = ah0;  *(bf16x8*)&Ah[arow][ak+8] = ah1;
    *(bf16x8*)&Am[arow][ak] = am0;  *(bf16x8*)&Am[arow][ak+8] = am1;
    *(bf16x8*)&Al[arow][ak] = al0;  *(bf16x8*)&Al[arow][ak+8] = al1;
    *(bf16x8*)&Bh[brow][bk] = bh8;
    *(bf16x8*)&Bm[brow][bk] = bm8;
    *(bf16x8*)&Bl[brow][bk] = bl8;
    __syncthreads();

    bf16x8 ahf[2], amf[2], alf[2];
#pragma unroll
    for (int ms = 0; ms < 2; ++ms) {
      int rr = wid*32 + ms*16 + bcol;
      ahf[ms] = *(const bf16x8*)&Ah[rr][lgrp*8];
      amf[ms] = *(const bf16x8*)&Am[rr][lgrp*8];
      alf[ms] = *(const bf16x8*)&Al[rr][lgrp*8];
    }
#pragma unroll
    for (int nt = 0; nt < 4; ++nt) {
      int nr = nt*16 + bcol;
      bf16x8 bh = *(const bf16x8*)&Bh[nr][lgrp*8];
      bf16x8 bm = *(const bf16x8*)&Bm[nr][lgrp*8];
      bf16x8 bl = *(const bf16x8*)&Bl[nr][lgrp*8];
#pragma unroll
      for (int ms = 0; ms < 2; ++ms) {
        acch[ms][nt] = __builtin_amdgcn_mfma_f32_16x16x32_bf16(ahf[ms], bh, acch[ms][nt], 0, 0, 0);
        accl[ms][nt] = __builtin_amdgcn_mfma_f32_16x16x32_bf16(ahf[ms], bm, accl[ms][nt], 0, 0, 0);
        accl[ms][nt] = __builtin_amdgcn_mfma_f32_16x16x32_bf16(amf[ms], bh, accl[ms][nt], 0, 0, 0);
        accl[ms][nt] = __builtin_amdgcn_mfma_f32_16x16x32_bf16(amf[ms], bm, accl[ms][nt], 0, 0, 0);
        accl[ms][nt] = __builtin_amdgcn_mfma_f32_16x16x32_bf16(ahf[ms], bl, accl[ms][nt], 0, 0, 0);
        accl[ms][nt] = __builtin_amdgcn_mfma_f32_16x16x32_bf16(alf[ms], bh, accl[ms][nt], 0, 0, 0);
      }
    }
  }

#pragma unroll
  for (int ms = 0; ms < 2; ++ms)
#pragma unroll
    for (int nt = 0; nt < 4; ++nt)
#pragma unroll
      for (int rv = 0; rv < 4; ++rv) {
        int m = m0 + wid*32 + ms*16 + lgrp*4 + rv;
        int n = n0 + nt*16 + bcol;
        out[(size_t)m * Dz + n] = (acch[ms][nt][rv] + accl[ms][nt][rv]) + bias[n];
      }
}

// ---- attention v11 (r18/r20 optimum: 384 us; plateau-verified) ------------
__global__ __launch_bounds__(256) void attn_topk(
    const float* __restrict__ q32g, const float* __restrict__ k32g,
    const short* __restrict__ kbfg, const float* __restrict__ v32,
    float* __restrict__ y)
{
  __shared__ float q_s[QBLK][DHz];
  __shared__ __align__(16) unsigned char ubuf[QBLK*CAND_MAX*6];
  __shared__ int bstar_s[QBLK];
  __shared__ int candcnt[QBLK];

  unsigned* hist = (unsigned*)ubuf;                   // [16][HSTR]
  float* candv = (float*)ubuf;                        // [16][CAND_MAX]
  unsigned short* candidx = (unsigned short*)(ubuf + QBLK*CAND_MAX*4);

  const int tid = threadIdx.x;
  const int bid0 = blockIdx.x;
  const int bh_f = (bid0 & 7) + 8 * (bid0 >> 10);
  const int qbf = (bid0 >> 3) & 127;
  const int h = bh_f & 15;
  const int bb = bh_f >> 4;
  const size_t bh = (size_t)(bb * Hz + h);
  const float* qg = q32g + (bh * Tz + (size_t)qbf * QBLK) * DHz;
  const float* kg32 = k32g + bh * Tz * DHz;
  const short* kb = kbfg + bh * Tz * DHz;
  const float* vg = v32 + bh * Tz * DHz;

  if (tid < QBLK) candcnt[tid] = 0;
  for (int i = tid; i < QBLK*HSTR; i += 256) hist[i] = 0u;
  {
    int r = tid >> 4, d4 = (tid & 15) * 4;
    *(float4*)&q_s[r][d4] = *(const float4*)&qg[r*DHz + d4];
  }
  __syncthreads();                                    // barrier 1

  const int lane = tid & 63;
  const int wid = tid >> 6;
  const int bcol = lane & 15;
  const int lgrp = lane >> 4;
  bf16x8 aF0, aF1;
#pragma unroll
  for (int e = 0; e < 8; ++e) {
    aF0[e] = f2bf(q_s[bcol][lgrp*8 + e]);
    aF1[e] = f2bf(q_s[bcol][32 + lgrp*8 + e]);
  }
  const int t0base = wid * 512;

  unsigned binreg[32];
#pragma unroll 4
  for (int tt = 0; tt < 32; ++tt) {
    const short* kbp = kb + (size_t)(t0base + tt*16 + bcol) * DHz;
    bf16x8 b0 = *(const bf16x8*)(kbp + lgrp*8);
    bf16x8 b1 = *(const bf16x8*)(kbp + 32 + lgrp*8);
    f32x4 c = {0.f, 0.f, 0.f, 0.f};
    c = __builtin_amdgcn_mfma_f32_16x16x32_bf16(aF0, b0, c, 0, 0, 0);
    c = __builtin_amdgcn_mfma_f32_16x16x32_bf16(aF1, b1, c, 0, 0, 0);
    unsigned bw = 0u;
#pragma unroll
    for (int j = 0; j < 4; ++j) {
      int bin = (int)((c[j] - SLO) * SBINR);
      bin = bin < 0 ? 0 : (bin > 255 ? 255 : bin);
      atomicAdd(&hist[(lgrp*4 + j)*HSTR + bin], 1u);
      bw |= ((unsigned)bin) << (8*j);
    }
    binreg[tt] = bw;
  }
  __syncthreads();                                    // barrier 2

  {
    int r = tid >> 4, i16 = tid & 15;
    int s = 0;
#pragma unroll
    for (int j = 0; j < 16; ++j) s += (int)hist[r*HSTR + i16*16 + j];
    int S = s;
#pragma unroll
    for (int off = 1; off < 16; off <<= 1) {
      int src = i16 + off;
      int v = __shfl(S, (lane & 48) | (src < 16 ? src : 15));
      S += (src < 16) ? v : 0;
    }
    unsigned long long blt = __ballot(S >= TOPKz);
    unsigned mask16 = (unsigned)((blt >> (lane & 48)) & 0xFFFFull);
    int istar = 31 - __builtin_clz(mask16);
    if (i16 == istar) {
      int cum = S - s;
      int b = istar * 16;
      for (int j = 15; j >= 0; --j) {
        cum += (int)hist[r*HSTR + istar*16 + j];
        if (cum >= TOPKz) { b = istar*16 + j; break; }
      }
      bstar_s[r] = b;
    }
  }
  __syncthreads();                                    // barrier 3 (hist dead)

  {
    int bc[4];
#pragma unroll
    for (int j = 0; j < 4; ++j) {
      int b = bstar_s[lgrp*4 + j] - 1;
      bc[j] = b < 0 ? 0 : b;
    }
#pragma unroll
    for (int tt = 0; tt < 32; ++tt) {
      unsigned bw = binreg[tt];
#pragma unroll
      for (int j = 0; j < 4; ++j) {
        int bin = (int)((bw >> (8*j)) & 255u);
        if (bin >= bc[j]) {
          int r = lgrp*4 + j;
          int p = atomicAdd(&candcnt[r], 1);
          if (p < CAND_MAX) candidx[r*CAND_MAX + p] = (unsigned short)(t0base + tt*16 + bcol);
        }
      }
    }
  }
  __syncthreads();                                    // barrier 4 (last)

  {
    const int r = tid >> 4, i16 = tid & 15;
    int n = candcnt[r]; if (n > CAND_MAX) n = CAND_MAX;

    for (int i = i16; i < n; i += 16) {
      int col = (int)candidx[r*CAND_MAX + i];
      const float* kpd = kg32 + (size_t)col * DHz;
      double s = 0.0;
#pragma unroll
      for (int d = 0; d < DHz; d += 4) {
        float4 k4 = *(const float4*)(kpd + d);
        s = fma((double)q_s[r][d+0], (double)k4.x, s);
        s = fma((double)q_s[r][d+1], (double)k4.y, s);
        s = fma((double)q_s[r][d+2], (double)k4.z, s);
        s = fma((double)q_s[r][d+3], (double)k4.w, s);
      }
      candv[r*CAND_MAX + i] = (float)s;
    }

    float myv[11];
    float mx = -3.0e38f;
#pragma unroll
    for (int j = 0; j < 11; ++j) {
      int i = i16 + j*16;
      float x = (i < n) ? candv[r*CAND_MAX + i] : -3.0e38f;
      myv[j] = x;
      mx = fmaxf(mx, x);
    }
#pragma unroll
    for (int m = 1; m < 16; m <<= 1) mx = fmaxf(mx, __shfl_xor(mx, m));

    float mn = 3.0e38f;
#pragma unroll
    for (int j = 0; j < 11; ++j) {
      int i = i16 + j*16;
      if (i < n) mn = fminf(mn, myv[j]);
    }
#pragma unroll
    for (int m = 1; m < 16; m <<= 1) mn = fminf(mn, __shfl_xor(mn, m));
    unsigned lo_u = f2s(mn);
    unsigned hi_u = f2s(mx) + 1u;
    while (hi_u - lo_u > 1u) {
      unsigned mid = lo_u + ((hi_u - lo_u) >> 1);
      float tv = s2f(mid);
      int cnt = 0;
#pragma unroll
      for (int j = 0; j < 11; ++j) cnt += (myv[j] >= tv) ? 1 : 0;
#pragma unroll
      for (int m = 1; m < 16; m <<= 1) cnt += __shfl_xor(cnt, m);
      if (cnt >= TOPKz) lo_u = mid; else hi_u = mid;
    }
    const float T = s2f(lo_u);

    int na = 0, nb = 0;
#pragma unroll
    for (int j = 0; j < 11; ++j) {
      float s = myv[j];
      if (s > T + BAND) na++;
      else if (s >= T - BAND) nb++;
    }
#pragma unroll
    for (int m = 1; m < 16; m <<= 1) {
      na += __shfl_xor(na, m);
      nb += __shfl_xor(nb, m);
    }
    const float wb = (float)(TOPKz - na) / (float)(nb > 0 ? nb : 1);

    float lsum = 0.f;
#pragma unroll
    for (int j = 0; j < 11; ++j) {
      int i = i16 + j*16;
      if (i < n) {
        float s = myv[j];
        float w = (s > T + BAND) ? 1.f : ((s >= T - BAND) ? wb : 0.f);
        float p = (w > 0.f) ? w * expf((s - mx) * 0.125f) : 0.f;
        candv[r*CAND_MAX + i] = p;
        lsum += p;
      }
    }
#pragma unroll
    for (int m = 1; m < 16; m <<= 1) lsum += __shfl_xor(lsum, m);
    const float rd = 1.0f / lsum;

    const int dg = i16 * 4;
    float4 o = make_float4(0.f, 0.f, 0.f, 0.f);
    for (int i = 0; i < n; ++i) {
      float p = candv[r*CAND_MAX + i];
      int idx = (int)candidx[r*CAND_MAX + i];
      float4 vv = *(const float4*)&vg[(size_t)idx*DHz + dg];
      float pw = p * rd;
      o.x = fmaf(pw, vv.x, o.x);
      o.y = fmaf(pw, vv.y, o.y);
      o.z = fmaf(pw, vv.z, o.z);
      o.w = fmaf(pw, vv.w, o.w);
    }
    float* yo = y + ((size_t)bb*Tz + (size_t)qbf*QBLK + r) * BNz + h*DHz + dg;
    *(float4*)yo = o;
  }
}

extern "C" void kernel_launch(void* const* d_in, const int* in_sizes, int n_in,
                              void* d_out, int out_size, void* d_ws, size_t ws_size,
                              hipStream_t stream)
{
  const float* x      = (const float*)d_in[0];
  const float* w_qkv  = (const float*)d_in[1];
  const float* b_qkv  = (const float*)d_in[2];
  const float* w_proj = (const float*)d_in[3];
  const float* b_proj = (const float*)d_in[4];
  float* out = (float*)d_out;

  const size_t E  = (size_t)Bz * Tz * Dz;        // 4,194,304
  const size_t Wq = (size_t)3 * BNz * Dz;        // 3,145,728
  const size_t Wp = (size_t)Dz * BNz;            // 1,048,576

  float* q32 = (float*)d_ws;           // 16 MB
  float* k32 = q32 + E;                // 16 MB
  short* kbf = (short*)(k32 + E);      // 8 MB
  float* v32 = (float*)(kbf + E);      // 16 MB
  float* y   = v32 + E;                // 16 MB
  short* sAh = (short*)(y + E);        // 8 MB
  short* sAm = sAh + E;                // 8 MB
  short* sAl = sAm + E;                // 8 MB
  short* sBh = sAl + E;                // 6 MB
  short* sBm = sBh + Wq;               // 6 MB
  short* sBl = sBm + Wq;               // 6 MB  (total 114 MB)

  split3<<<(int)(E/4/256), 256, 0, stream>>>(x, sAh, sAm, sAl, (int)(E/4));
  split3<<<(int)(Wq/4/256), 256, 0, stream>>>(w_qkv, sBh, sBm, sBl, (int)(Wq/4));
  qkv_gemm_v2<<<dim3((3*BNz)/64, (Bz*Tz)/128), 256, 0, stream>>>(
      sAh, sAm, sAl, sBh, sBm, sBl, b_qkv, q32, k32, kbf, v32);
  attn_topk<<<Bz*Hz*(Tz/QBLK), 256, 0, stream>>>(q32, k32, kbf, v32, y);
  split3<<<(int)(E/4/256), 256, 0, stream>>>(y, sAh, sAm, sAl, (int)(E/4));
  split3<<<(int)(Wp/4/256), 256, 0, stream>>>(w_proj, sBh, sBm, sBl, (int)(Wp/4));
  proj_gemm_v2<<<dim3(Dz/64, (Bz*Tz)/128), 256, 0, stream>>>(
      sAh, sAm, sAl, sBh, sBm, sBl, b_proj, out);
}